// Round 3
// baseline (157.200 us; speedup 1.0000x reference)
//
#include <hip/hip_runtime.h>
#include <math.h>

// CapsuleLayer dynamic routing, fused single kernel. R3: same structure as
// R2 (priors in registers, float4 pri[18]/thread) but occupancy PINNED via
// amdgpu_waves_per_eu(4,4) -> 128-VGPR budget. R2's launch_bounds(256,4)
// let the backend target 8 waves/EU (64 VGPR) and spill pri[] to scratch
// (WRITE_SIZE 23 MB). Phase A stays fully unrolled: pri[p] must be
// compile-time-indexed or it lands in scratch.
// Block order c-major so concurrent blocks share W[c] (589 KB, L2-hot).

#define NBATCH 256
#define NC 10
#define NR 1152
#define IC 8
#define OC 16
#define NITER 3
#define RPT 18   // NR / 64 r-values per thread

__device__ __forceinline__ float wave_sum(float v) {
#pragma unroll
    for (int m = 1; m <= 32; m <<= 1) v += __shfl_xor(v, m, 64);
    return v;
}
__device__ __forceinline__ float wave_max(float v) {
#pragma unroll
    for (int m = 1; m <= 32; m <<= 1) v = fmaxf(v, __shfl_xor(v, m, 64));
    return v;
}

__global__ __launch_bounds__(256)
__attribute__((amdgpu_waves_per_eu(4, 4)))   // pin 4 waves/EU -> 128 VGPR, no spill
void caps_route(
    const float* __restrict__ x,   // [B, NR, IC]
    const float* __restrict__ W,   // [NC, NR, IC, OC]
    float* __restrict__ out)       // [B, NC, OC]
{
    __shared__ float logit[NR];    // collapsed logits (broadcast over OC)
    __shared__ float red[64];      // cross-wave reduction scratch
    __shared__ float vout[OC];     // current output vector

    const int t    = threadIdx.x;
    const int og   = t & 3;        // o-quad (o = og*4+j)
    const int rr   = t >> 2;       // 0..63
    const int lane = t & 63;
    const int wid  = t >> 6;

    const int c = blockIdx.x >> 8; // c-major: 256 consecutive blocks share W[c]
    const int b = blockIdx.x & 255;

    // ---------------- Phase A: pri[p] = priors[r=rr+64p][o-quad og] --------
    float4 pri[RPT];
    const float4* __restrict__ xb = (const float4*)(x + (size_t)b * (NR * IC));
    const float4* __restrict__ wb = (const float4*)(W + (size_t)c * (NR * IC * OC));
#pragma unroll
    for (int p = 0; p < RPT; ++p) {
        const int r = rr + (p << 6);
        float4 xa = xb[2 * r];
        float4 xc = xb[2 * r + 1];
        const float4* wp = wb + (size_t)r * 32 + og; // float4 idx (r*8+i)*4+og
        float xs[8] = {xa.x, xa.y, xa.z, xa.w, xc.x, xc.y, xc.z, xc.w};
        float4 acc = make_float4(0.f, 0.f, 0.f, 0.f);
#pragma unroll
        for (int i = 0; i < 8; ++i) {
            float4 w = wp[i * 4];
            acc.x = fmaf(xs[i], w.x, acc.x);
            acc.y = fmaf(xs[i], w.y, acc.y);
            acc.z = fmaf(xs[i], w.z, acc.z);
            acc.w = fmaf(xs[i], w.w, acc.w);
        }
        pri[p] = acc;
    }

    // ---------------- Phase B: 3 routing iterations -------------------------
    for (int it = 0; it < NITER; ++it) {
        const bool uni = (it == 0); // softmax of zeros = uniform
        float m = 0.f, invd = 0.f;
        if (!uni) {
            float lm = -3.4e38f;
            for (int k = 0; k < 5; ++k) {
                int r = t + (k << 8);
                if (r < NR) lm = fmaxf(lm, logit[r]);
            }
            lm = wave_max(lm);
            if (lane == 0) red[wid] = lm;
            __syncthreads();
            m = fmaxf(fmaxf(red[0], red[1]), fmaxf(red[2], red[3]));
            float ls = 0.f;
            for (int k = 0; k < 5; ++k) {
                int r = t + (k << 8);
                if (r < NR) ls += __expf(logit[r] - m);
            }
            ls = wave_sum(ls);
            __syncthreads();              // max reads done before red rewrite
            if (lane == 0) red[wid] = ls;
            __syncthreads();
            invd = 1.f / (red[0] + red[1] + red[2] + red[3]);
        }

        // s[o] partial = sum over owned r of probs[r]*pri[r][o]
        float4 s4 = make_float4(0.f, 0.f, 0.f, 0.f);
#pragma unroll
        for (int k = 0; k < RPT; ++k) {
            float wgt = 1.0f;
            if (!uni) wgt = __expf(logit[rr + (k << 6)] - m);
            s4.x = fmaf(wgt, pri[k].x, s4.x);
            s4.y = fmaf(wgt, pri[k].y, s4.y);
            s4.z = fmaf(wgt, pri[k].z, s4.z);
            s4.w = fmaf(wgt, pri[k].w, s4.w);
        }
        // reduce over the 16 rr slots (same og) within each wave
#pragma unroll
        for (int msk = 4; msk <= 32; msk <<= 1) {
            s4.x += __shfl_xor(s4.x, msk, 64);
            s4.y += __shfl_xor(s4.y, msk, 64);
            s4.z += __shfl_xor(s4.z, msk, 64);
            s4.w += __shfl_xor(s4.w, msk, 64);
        }
        __syncthreads();                  // denom/squash reads done
        if (lane < 4) ((float4*)red)[wid * 4 + og] = s4; // red[wid*16 + o]
        __syncthreads();

        if (t < OC) {                     // 16 threads of wave 0
            float s = red[t] + red[16 + t] + red[32 + t] + red[48 + t];
            s *= uni ? (1.0f / 1152.0f) : invd;
            float sq = s * s;
#pragma unroll
            for (int msk = 1; msk <= 8; msk <<= 1) sq += __shfl_xor(sq, msk, 64);
            float v = s * (sqrtf(sq) / (1.0f + sq)); // squash
            if (it == NITER - 1) out[((size_t)b * NC + c) * OC + t] = v;
            else vout[t] = v;
        }
        __syncthreads();

        if (it < NITER - 1) {
            // logit[r] += sum_o pri[r][o]*v[o]
            float4 v4 = ((const float4*)vout)[og];
#pragma unroll
            for (int k = 0; k < RPT; ++k) {
                const int r = rr + (k << 6);
                float d = pri[k].x * v4.x + pri[k].y * v4.y +
                          pri[k].z * v4.z + pri[k].w * v4.w;
                d += __shfl_xor(d, 1, 64);
                d += __shfl_xor(d, 2, 64);
                if (og == 0) {
                    if (it == 0) logit[r] = d;   // logits start at zero
                    else         logit[r] += d;
                }
            }
            __syncthreads();
        }
    }
}

extern "C" void kernel_launch(void* const* d_in, const int* in_sizes, int n_in,
                              void* d_out, int out_size, void* d_ws, size_t ws_size,
                              hipStream_t stream) {
    const float* x = (const float*)d_in[0];
    const float* W = (const float*)d_in[1];
    float* out = (float*)d_out;
    caps_route<<<dim3(NC * NBATCH), dim3(256), 0, stream>>>(x, W, out);
}

// Round 4
// 137.941 us; speedup vs baseline: 1.1396x; 1.1396x over previous
//
#include <hip/hip_runtime.h>
#include <math.h>

// CapsuleLayer dynamic routing, fused single kernel. R4.
// Root cause found in R2/R3: backend derives VGPR budget from LDS-based
// occupancy target (5 KB LDS -> 8 waves/EU -> 64-VGPR cap) and demoted the
// 72-reg pri[18] array to SCRATCH wholesale (VGPR_Count=64, WRITE_SIZE 73MB).
// Fix: 512-thread blocks -> pri[9] = 36 VGPRs (demand ~70), and stage x[b]
// (36 KB) in LDS, which both removes 4x-redundant x reads AND pushes the
// LDS-derived occupancy target to 3 blocks/CU = 6 waves/EU = 84-VGPR cap.
// Registers stay registers. Block order c-major: concurrent blocks share
// W[c] (589 KB) in L2.

#define NBATCH 256
#define NC 10
#define NR 1152
#define IC 8
#define OC 16
#define NITER 3
#define T 512
#define RPT 9    // NR / 128 r-values per thread

__device__ __forceinline__ float wave_sum(float v) {
#pragma unroll
    for (int m = 1; m <= 32; m <<= 1) v += __shfl_xor(v, m, 64);
    return v;
}
__device__ __forceinline__ float wave_max(float v) {
#pragma unroll
    for (int m = 1; m <= 32; m <<= 1) v = fmaxf(v, __shfl_xor(v, m, 64));
    return v;
}

__global__ __launch_bounds__(T) void caps_route(
    const float* __restrict__ x,   // [B, NR, IC]
    const float* __restrict__ W,   // [NC, NR, IC, OC]
    float* __restrict__ out)       // [B, NC, OC]
{
    __shared__ float4 xs4[NR * 2];   // x[b] slice, 36 KB
    __shared__ float logit[NR];      // collapsed logits (broadcast over OC)
    __shared__ float red[128];       // cross-wave reduction scratch (8 waves x 16)
    __shared__ float vout[OC];       // current output vector

    const int t    = threadIdx.x;
    const int og   = t & 3;          // o-quad (o = og*4+j)
    const int rr   = t >> 2;         // 0..127
    const int lane = t & 63;
    const int wid  = t >> 6;         // 0..7

    const int c = blockIdx.x >> 8;   // c-major: 256 consecutive blocks share W[c]
    const int b = blockIdx.x & 255;

    // ---------------- stage x[b] into LDS (coalesced float4) ---------------
    const float4* __restrict__ xb = (const float4*)(x + (size_t)b * (NR * IC));
    for (int k = t; k < NR * 2; k += T) xs4[k] = xb[k];
    __syncthreads();

    // ---------------- Phase A: pri[p] = priors[r=rr+128p][o-quad og] -------
    float4 pri[RPT];
    const float4* __restrict__ wb = (const float4*)(W + (size_t)c * (NR * IC * OC));
#pragma unroll
    for (int p = 0; p < RPT; ++p) {
        const int r = rr + (p << 7);
        float4 xa = xs4[2 * r];
        float4 xc = xs4[2 * r + 1];
        const float4* wp = wb + (size_t)r * 32 + og; // float4 idx (r*8+i)*4+og
        float xv[8] = {xa.x, xa.y, xa.z, xa.w, xc.x, xc.y, xc.z, xc.w};
        float4 acc = make_float4(0.f, 0.f, 0.f, 0.f);
#pragma unroll
        for (int i = 0; i < 8; ++i) {
            float4 w = wp[i * 4];
            acc.x = fmaf(xv[i], w.x, acc.x);
            acc.y = fmaf(xv[i], w.y, acc.y);
            acc.z = fmaf(xv[i], w.z, acc.z);
            acc.w = fmaf(xv[i], w.w, acc.w);
        }
        pri[p] = acc;
    }

    // ---------------- Phase B: 3 routing iterations -------------------------
    for (int it = 0; it < NITER; ++it) {
        const bool uni = (it == 0);  // softmax of zeros = uniform
        float m = 0.f, invd = 0.f;
        if (!uni) {
            float lm = -3.4e38f;
#pragma unroll
            for (int k = 0; k < 3; ++k) {
                int r = t + (k << 9);
                if (r < NR) lm = fmaxf(lm, logit[r]);
            }
            lm = wave_max(lm);
            if (lane == 0) red[wid] = lm;
            __syncthreads();
            m = red[0];
#pragma unroll
            for (int w = 1; w < 8; ++w) m = fmaxf(m, red[w]);
            float ls = 0.f;
#pragma unroll
            for (int k = 0; k < 3; ++k) {
                int r = t + (k << 9);
                if (r < NR) ls += __expf(logit[r] - m);
            }
            ls = wave_sum(ls);
            __syncthreads();             // max reads done before red rewrite
            if (lane == 0) red[wid] = ls;
            __syncthreads();
            float den = red[0];
#pragma unroll
            for (int w = 1; w < 8; ++w) den += red[w];
            invd = 1.f / den;
        }

        // s[o] partial = sum over owned r of probs[r]*pri[r][o]
        float4 s4 = make_float4(0.f, 0.f, 0.f, 0.f);
#pragma unroll
        for (int k = 0; k < RPT; ++k) {
            float wgt = 1.0f;
            if (!uni) wgt = __expf(logit[rr + (k << 7)] - m);
            s4.x = fmaf(wgt, pri[k].x, s4.x);
            s4.y = fmaf(wgt, pri[k].y, s4.y);
            s4.z = fmaf(wgt, pri[k].z, s4.z);
            s4.w = fmaf(wgt, pri[k].w, s4.w);
        }
        // reduce over the 16 rr slots (same og) within each wave
#pragma unroll
        for (int msk = 4; msk <= 32; msk <<= 1) {
            s4.x += __shfl_xor(s4.x, msk, 64);
            s4.y += __shfl_xor(s4.y, msk, 64);
            s4.z += __shfl_xor(s4.z, msk, 64);
            s4.w += __shfl_xor(s4.w, msk, 64);
        }
        __syncthreads();                 // denom/prev-red reads done
        if (lane < 4) ((float4*)red)[wid * 4 + og] = s4; // red[wid*16 + o]
        __syncthreads();

        if (t < OC) {                    // 16 threads of wave 0
            float s = 0.f;
#pragma unroll
            for (int w = 0; w < 8; ++w) s += red[w * 16 + t];
            s *= uni ? (1.0f / 1152.0f) : invd;
            float sq = s * s;
#pragma unroll
            for (int msk = 1; msk <= 8; msk <<= 1) sq += __shfl_xor(sq, msk, 64);
            float v = s * (sqrtf(sq) / (1.0f + sq)); // squash
            if (it == NITER - 1) out[((size_t)b * NC + c) * OC + t] = v;
            else vout[t] = v;
        }
        __syncthreads();

        if (it < NITER - 1) {
            // logit[r] += sum_o pri[r][o]*v[o]
            float4 v4 = ((const float4*)vout)[og];
#pragma unroll
            for (int k = 0; k < RPT; ++k) {
                const int r = rr + (k << 7);
                float d = pri[k].x * v4.x + pri[k].y * v4.y +
                          pri[k].z * v4.z + pri[k].w * v4.w;
                d += __shfl_xor(d, 1, 64);
                d += __shfl_xor(d, 2, 64);
                if (og == 0) {
                    if (it == 0) logit[r] = d;   // logits start at zero
                    else         logit[r] += d;
                }
            }
            __syncthreads();
        }
    }
}

extern "C" void kernel_launch(void* const* d_in, const int* in_sizes, int n_in,
                              void* d_out, int out_size, void* d_ws, size_t ws_size,
                              hipStream_t stream) {
    const float* x = (const float*)d_in[0];
    const float* W = (const float*)d_in[1];
    float* out = (float*)d_out;
    caps_route<<<dim3(NC * NBATCH), dim3(T), 0, stream>>>(x, W, out);
}